// Round 2
// baseline (315.659 us; speedup 1.0000x reference)
//
#include <hip/hip_runtime.h>
#include <hip/hip_bf16.h>

// LSTMCell fused: ifgo = [x0 h0 x1 h1] @ W  (M=1024, N=8192, K=4096) + gates.
// Round 7: lstm_mm gets double-buffered LDS with EARLY-ISSUE staging
// (T3-minimal): per K-step, issue next tile's 8 global_load_lds BEFORE the
// ds_read+MFMA phase, so the barrier's vmcnt(0) drain overlaps with compute
// instead of stalling cold (round-1 counters: MfmaUtil 27%, HBM 14% -> pure
// latency/drain-bound). One __syncthreads per iter, no inline asm, same
// verified swizzle contract. LDS 64 KB -> 2 blocks/CU (launch_bounds 256,2).
// prep_all unchanged except full unroll of phase-1 loads (16 in flight).

typedef short bf16x8 __attribute__((ext_vector_type(8)));   // 8 bf16 (4 VGPRs)
typedef float f32x4  __attribute__((ext_vector_type(4)));

__device__ __forceinline__ unsigned pkcvt(float a, float b) {
#if defined(__has_builtin) && __has_builtin(__builtin_amdgcn_cvt_pk_bf16_f32)
  typedef __bf16 bf16x2_t __attribute__((ext_vector_type(2)));
  bf16x2_t r = __builtin_amdgcn_cvt_pk_bf16_f32(a, b);
  union { bf16x2_t v; unsigned u; } cv; cv.v = r;
  return cv.u;
#else
  unsigned ua = __float_as_uint(a), ub = __float_as_uint(b);
  ua = (ua + 0x7fffu + ((ua >> 16) & 1u)) >> 16;
  ub = (ub + 0x7fffu + ((ub >> 16) & 1u)) & 0xffff0000u;
  return ua | ub;
#endif
}

union pk8 { unsigned u[4]; bf16x8 v; };

__device__ __forceinline__ void gl_lds16(const void* g, void* l) {
  __builtin_amdgcn_global_load_lds(
      (const __attribute__((address_space(1))) unsigned*)g,
      (__attribute__((address_space(3))) unsigned*)l, 16, 0, 0);
}

// ---------- merged prep: W transpose (blocks 0..2047) + xh convert (2048..4095) ----------
// W part: tile = 64 u x 4 gates x 64 k per block. Output wsB[n*4096 + c][k]
// bf16, c = 4*u + gate, with 16B chunk pc of each 64k-window holding logical
// chunk pc ^ (c&7)  (pre-swizzle contract of lstm_mm, unchanged).
__global__ __launch_bounds__(256)
void prep_all(const float* __restrict__ x, const float* __restrict__ h,
              const float* __restrict__ W, void* wsAv, void* wsBv)
{
  __shared__ short Ls[64 * 258];   // 64 k-rows x (4 gates * 64 u + 2 pad) = 33 KB
  const int t   = threadIdx.x;
  const int bid = blockIdx.x;

  if (bid < 2048) {
    // ---- W transpose ----
    const int utile = bid & 15;              // 16 u-tiles of 64
    const int ktile = (bid >> 4) & 63;       // 64 k-tiles of 64
    const int n     = bid >> 10;             // 2 n-splits
    const int u0    = utile * 64;
    const int k0    = ktile * 64;
    const int kq    = k0 >> 11;              // k-tile lies in one kq slab
    const int krow0 = k0 & 2047;

    // phase 1: wave = gate; per instr 4 k-rows x 256B contiguous float4 spans.
    const int g    = t >> 6;                 // gate = wave id
    const int l15  = t & 15;                 // u within segment (x4 floats)
    const int rsel = (t >> 4) & 3;           // k-row within quad
    const float* wbase = W + ((size_t)(kq * 2 + n) * 2048 + krow0) * 4096
                           + g * 1024 + u0 + l15 * 4;
    #pragma unroll
    for (int i = 0; i < 16; ++i) {
      const int kk = i * 4 + rsel;           // 0..63
      const float4 v = *(const float4*)(wbase + (size_t)kk * 4096);
      const int ad = kk * 258 + g * 64 + l15 * 4;   // de-interleaved row layout
      *(unsigned*)&Ls[ad]     = pkcvt(v.x, v.y);
      *(unsigned*)&Ls[ad + 2] = pkcvt(v.z, v.w);
    }
    __syncthreads();

    // phase 2: gather 8 k-consecutive bf16 per 16B chunk; wave stores
    // 8 full 128B rows per instr (fully coalesced), chunk-XOR pre-swizzled.
    const int cg = t >> 3;                   // 0..31 c-group
    const int pc = t & 7;                    // physical chunk
    char* outb = (char*)wsBv + (size_t)(n * 4096 + u0 * 4) * 8192
               + (size_t)k0 * 2 + pc * 16;
    #pragma unroll
    for (int j2 = 0; j2 < 8; ++j2) {
      const int c_l  = j2 * 32 + cg;         // 0..255 within tile
      const int gg   = c_l & 3;
      const int uloc = c_l >> 2;
      const int lc   = pc ^ (c_l & 7);       // logical chunk (swizzle contract)
      const int base = lc * 8 * 258 + gg * 64 + uloc;
      pk8 o;
      #pragma unroll
      for (int q = 0; q < 4; ++q) {
        const unsigned s0 = (unsigned short)Ls[base + (2 * q)     * 258];
        const unsigned s1 = (unsigned short)Ls[base + (2 * q + 1) * 258];
        o.u[q] = s0 | (s1 << 16);
      }
      *(bf16x8*)(outb + (size_t)c_l * 8192) = o.v;
    }
  } else {
    // ---- xh -> bf16 wsA[row][k], chunk pre-XORed by row&7 (unchanged) ----
    const int gid = (bid - 2048) * 256 + t;  // 524288 total
    const int row = gid >> 9;
    const int r9  = gid & 511;
    const int kt  = r9 >> 3;
    const int pcx = r9 & 7;
    const int lcx = pcx ^ (row & 7);
    const int kk0 = kt * 64 + lcx * 8;
    const int blk = kk0 >> 10;               // 0..3 -> x0,h0,x1,h1
    const float* src = ((blk & 1) ? h : x) + row * 2048 + (blk >> 1) * 1024 + (kk0 & 1023);
    const float4 p0 = ((const float4*)src)[0];
    const float4 p1 = ((const float4*)src)[1];
    pk8 o;
    o.u[0] = pkcvt(p0.x, p0.y); o.u[1] = pkcvt(p0.z, p0.w);
    o.u[2] = pkcvt(p1.x, p1.y); o.u[3] = pkcvt(p1.z, p1.w);
    *(bf16x8*)((char*)wsAv + (size_t)row * 8192 + kt * 128 + pcx * 16) = o.v;
  }
}

// ---------- main: m97-structure GEMM, double-buffered early-issue staging ----------
__global__ __launch_bounds__(256, 2)
void lstm_mm(const void* wsAv, const void* wsBv,
             const float* __restrict__ cin, float* __restrict__ out)
{
  __shared__ short As[2][128 * 64];   // 2 x 16 KB, pre-swizzled via linear copy
  __shared__ short Bs[2][128 * 64];   // 2 x 16 KB

  const int tid  = threadIdx.x;
  const int lane = tid & 63;
  const int wid  = tid >> 6;
  const int wr   = wid >> 1;
  const int wc   = wid & 1;

  const int bid     = blockIdx.x;                 // 512 = 8 rowblk x 64 colblk
  const int rowblk  = bid >> 6;                   // bid%8==colblk%8 -> XCD share
  const int colblk  = bid & 63;
  const int n       = colblk >> 5;
  const int u0      = (colblk & 31) * 32;
  const int rowbase = rowblk * 128;

  const int am   = lane & 15;
  const int quad = lane >> 4;
  const int rA   = lane >> 3;                     // row within 8-row group
  const int pcA  = lane & 7;

  const char* wsA = (const char*)wsAv;
  const char* wsB = (const char*)wsBv;
  const size_t aRowBase = (size_t)(rowbase + wid * 32) * 8192;
  const size_t bRowBase = (size_t)(n * 4096 + 4 * u0 + wid * 32) * 8192;

  f32x4 acc[4][4];
  const f32x4 zero = {0.f, 0.f, 0.f, 0.f};
  #pragma unroll
  for (int i = 0; i < 4; ++i)
    #pragma unroll
    for (int j = 0; j < 4; ++j) acc[i][j] = zero;

  // stage K-tile kt into buffer b (each instr: 64 lanes x 16B = 8 rows x 128B,
  // LDS dest wave-uniform; source pre-swizzled so linear copy lands right).
  auto stage = [&](int kt, int b) {
    #pragma unroll
    for (int q = 0; q < 4; ++q) {
      gl_lds16(wsA + aRowBase + (size_t)(q * 8 + rA) * 8192 + kt * 128 + pcA * 16,
               &As[b][(wid * 32 + q * 8) * 64]);
      gl_lds16(wsB + bRowBase + (size_t)(q * 8 + rA) * 8192 + kt * 128 + pcA * 16,
               &Bs[b][(wid * 32 + q * 8) * 64]);
    }
  };

  stage(0, 0);
  __syncthreads();                 // drain stage(0)

  for (int kt = 0; kt < 64; ++kt) {
    const int cur = kt & 1;
    if (kt < 63) stage(kt + 1, cur ^ 1);   // issue EARLY: overlaps compute below

    #pragma unroll
    for (int s = 0; s < 2; ++s) {
      const int sw = ((s * 4 + quad) ^ (am & 7)) * 8;   // zero-conflict (verified)
      bf16x8 af[4], bfr[4];
      #pragma unroll
      for (int tm = 0; tm < 4; ++tm)
        af[tm] = *(const bf16x8*)&As[cur][(wr * 64 + tm * 16 + am) * 64 + sw];
      #pragma unroll
      for (int tn = 0; tn < 4; ++tn)
        bfr[tn] = *(const bf16x8*)&Bs[cur][(wc * 64 + tn * 16 + am) * 64 + sw];
      #pragma unroll
      for (int tm = 0; tm < 4; ++tm)
        #pragma unroll
        for (int tn = 0; tn < 4; ++tn)
          acc[tm][tn] = __builtin_amdgcn_mfma_f32_16x16x32_bf16(
              af[tm], bfr[tn], acc[tm][tn], 0, 0, 0);
    }

    // barrier's implicit vmcnt(0) drains stage(kt+1) -- issued ~full compute
    // phase earlier, so the wait is mostly satisfied. Also orders this iter's
    // ds_reads (completed: they fed the MFMAs) before next overwrite.
    __syncthreads();
  }

  // fused LSTM epilogue: C/D col = lane&15 (c_il = 4*u + gate), row = quad*4+reg.
  const int BU   = 1024 * 2048;
  const int g    = lane & 3;
  const int base = lane & ~3;
  #pragma unroll
  for (int tn = 0; tn < 4; ++tn) {
    const int cil = wc * 64 + tn * 16 + am;
    const int col = n * 1024 + u0 + (cil >> 2);
    #pragma unroll
    for (int tm = 0; tm < 4; ++tm) {
      const int brow0 = rowbase + wr * 64 + tm * 16 + quad * 4;
      #pragma unroll
      for (int r = 0; r < 4; ++r) {
        const int brow = brow0 + r;
        const float val = acc[tm][tn][r];
        const float xs  = (g == 2) ? 2.f * val : val;       // tanh via sigmoid
        const float sg  = 1.f / (1.f + __expf(-xs));
        const float act = (g == 2) ? (2.f * sg - 1.f) : sg;
        const float ig = __shfl(act, base + 0, 64);
        const float fg = __shfl(act, base + 1, 64);
        const float gg = __shfl(act, base + 2, 64);
        const float og = __shfl(act, base + 3, 64);
        const float cold = cin[brow * 2048 + col];
        const float nc = fg * cold + ig * gg;
        const float th = 1.f - 2.f / (1.f + __expf(2.f * nc));
        const float nh = og * th;
        if (g == 0) out[brow * 2048 + col]      = nh;
        if (g == 1) out[BU + brow * 2048 + col] = nc;
      }
    }
  }
}

// ---------- fallback: round-4 fused kernel (used when ws too small) ----------
__global__ __launch_bounds__(512, 4)
void lstm_fused_fb(const float* __restrict__ x, const float* __restrict__ h,
                   const float* __restrict__ cin, const float* __restrict__ W,
                   float* __restrict__ out)
{
  __shared__ short As[128 * 64];
  __shared__ short Bs[128 * 64];
  const int tid  = threadIdx.x;
  const int lane = tid & 63;
  const int wid  = tid >> 6;
  const int wr   = wid >> 2;
  const int wq   = wid & 3;
  const int bid     = blockIdx.x;
  const int rowblk  = bid >> 6;
  const int colblk  = bid & 63;
  const int n       = colblk >> 5;
  const int u0      = (colblk & 31) * 32;
  const int rowbase = rowblk * 128;
  const int ar = tid >> 2;
  const int aq = tid & 3;
  const int bc   = tid & 127;
  const int bgt  = bc & 3;
  const int bu   = bc >> 2;
  const int kgrp = tid >> 7;
  const int gcol = bgt * 1024 + u0 + bu;
  const int am   = lane & 15;
  const int quad = lane >> 4;

  f32x4 acc[4][2];
  const f32x4 zero = {0.f, 0.f, 0.f, 0.f};
  #pragma unroll
  for (int i = 0; i < 4; ++i)
    #pragma unroll
    for (int j = 0; j < 2; ++j) acc[i][j] = zero;

  float4 areg[4];
  float  breg[16];
  auto load_tiles = [&](int kt) {
    const int blk = kt >> 4;
    const float* asrc = (blk & 1) ? h : x;
    const int cb = (blk >> 1) * 1024 + (kt & 15) * 64;
    const float4* p = (const float4*)(asrc + (rowbase + ar) * 2048 + cb + aq * 16);
    #pragma unroll
    for (int q = 0; q < 4; ++q) areg[q] = p[q];
    const int kq = kt >> 5;
    const float* wp = W + ((kq * 2 + n) * 2048 + (kt & 31) * 64 + kgrp * 16) * 4096 + gcol;
    #pragma unroll
    for (int j = 0; j < 16; ++j) breg[j] = wp[j * 4096];
  };
  load_tiles(0);
  for (int kt = 0; kt < 64; ++kt) {
    bf16x8 aw[2];
    {
      pk8 p0, p1;
      p0.u[0] = pkcvt(areg[0].x, areg[0].y); p0.u[1] = pkcvt(areg[0].z, areg[0].w);
      p0.u[2] = pkcvt(areg[1].x, areg[1].y); p0.u[3] = pkcvt(areg[1].z, areg[1].w);
      p1.u[0] = pkcvt(areg[2].x, areg[2].y); p1.u[1] = pkcvt(areg[2].z, areg[2].w);
      p1.u[2] = pkcvt(areg[3].x, areg[3].y); p1.u[3] = pkcvt(areg[3].z, areg[3].w);
      aw[0] = p0.v; aw[1] = p1.v;
    }
    bf16x8 bw[2];
    {
      pk8 q0, q1;
      #pragma unroll
      for (int j = 0; j < 4; ++j) {
        q0.u[j] = pkcvt(breg[2 * j],     breg[2 * j + 1]);
        q1.u[j] = pkcvt(breg[8 + 2 * j], breg[8 + 2 * j + 1]);
      }
      bw[0] = q0.v; bw[1] = q1.v;
    }
    __syncthreads();
    #pragma unroll
    for (int hh = 0; hh < 2; ++hh)
      *(bf16x8*)&As[ar * 64 + (((aq * 2 + hh) ^ (ar & 7)) * 8)] = aw[hh];
    #pragma unroll
    for (int hh = 0; hh < 2; ++hh)
      *(bf16x8*)&Bs[bc * 64 + (((kgrp * 2 + hh) ^ (bc & 7)) * 8)] = bw[hh];
    __syncthreads();
    if (kt < 63) load_tiles(kt + 1);
    #pragma unroll
    for (int s = 0; s < 2; ++s) {
      const int sw = ((s * 4 + quad) ^ (am & 7)) * 8;
      bf16x8 af[4], bfr[2];
      #pragma unroll
      for (int tm = 0; tm < 4; ++tm)
        af[tm] = *(const bf16x8*)&As[(wr * 64 + tm * 16 + am) * 64 + sw];
      #pragma unroll
      for (int tn = 0; tn < 2; ++tn)
        bfr[tn] = *(const bf16x8*)&Bs[(wq * 32 + tn * 16 + am) * 64 + sw];
      #pragma unroll
      for (int tm = 0; tm < 4; ++tm)
        #pragma unroll
        for (int tn = 0; tn < 2; ++tn)
          acc[tm][tn] = __builtin_amdgcn_mfma_f32_16x16x32_bf16(
              af[tm], bfr[tn], acc[tm][tn], 0, 0, 0);
    }
  }
  const int BU   = 1024 * 2048;
  const int g    = lane & 3;
  const int base = lane & ~3;
  #pragma unroll
  for (int tn = 0; tn < 2; ++tn) {
    const int cil = wq * 32 + tn * 16 + am;
    const int col = n * 1024 + u0 + (cil >> 2);
    #pragma unroll
    for (int tm = 0; tm < 4; ++tm) {
      const int brow0 = rowbase + wr * 64 + tm * 16 + quad * 4;
      #pragma unroll
      for (int r = 0; r < 4; ++r) {
        const int brow = brow0 + r;
        const float val = acc[tm][tn][r];
        const float xs  = (g == 2) ? 2.f * val : val;
        const float sg  = 1.f / (1.f + __expf(-xs));
        const float act = (g == 2) ? (2.f * sg - 1.f) : sg;
        const float ig = __shfl(act, base + 0, 64);
        const float fg = __shfl(act, base + 1, 64);
        const float gg = __shfl(act, base + 2, 64);
        const float og = __shfl(act, base + 3, 64);
        const float cold = cin[brow * 2048 + col];
        const float nc = fg * cold + ig * gg;
        const float th = 1.f - 2.f / (1.f + __expf(2.f * nc));
        const float nh = og * th;
        if (g == 0) out[brow * 2048 + col]      = nh;
        if (g == 1) out[BU + brow * 2048 + col] = nc;
      }
    }
  }
}

extern "C" void kernel_launch(void* const* d_in, const int* in_sizes, int n_in,
                              void* d_out, int out_size, void* d_ws, size_t ws_size,
                              hipStream_t stream) {
  const float* x = (const float*)d_in[0];
  const float* h = (const float*)d_in[1];
  const float* c = (const float*)d_in[2];
  const float* W = (const float*)d_in[3];
  float* out = (float*)d_out;

  const size_t WSA_BYTES = (size_t)1024 * 4096 * 2;        //  8 MB bf16 xh
  const size_t WSB_BYTES = (size_t)2 * 4096 * 4096 * 2;    // 67 MB bf16 W^T
  if (ws_size >= WSA_BYTES + WSB_BYTES) {
    char* wsA = (char*)d_ws;
    char* wsB = (char*)d_ws + WSA_BYTES;
    // blocks 0..2047: W transpose (long pole, dispatched first);
    // blocks 2048..4095: xh convert (backfills, overlaps the W stream).
    prep_all<<<dim3(4096), dim3(256), 0, stream>>>(x, h, W, wsA, wsB);
    lstm_mm<<<dim3(512), dim3(256), 0, stream>>>(wsA, wsB, c, out);
  } else {
    lstm_fused_fb<<<dim3(512), dim3(512), 0, stream>>>(x, h, c, W, out);
  }
}

// Round 4
// 301.860 us; speedup vs baseline: 1.0457x; 1.0457x over previous
//
#include <hip/hip_runtime.h>
#include <hip/hip_bf16.h>

// LSTMCell fused: ifgo = [x0 h0 x1 h1] @ W  (M=1024, N=8192, K=4096) + gates.
// Round 9: RESUBMIT of round 8 (container infra failure, not a kernel error).
// lstm_mm = round-6/R1 single-buffer loop (verified 102us; dbuf regressed to
// 160us via compiler vmcnt(0) before ds_read). prep keeps full-unroll phase 1
// (R2's hidden win: prep was latency-bound, ~100->~45us). Epilogue LDS bounce:
// cin staged coalesced into 16KB CinL, nh/nc scattered into As/Bs (dead after
// last MFMA, reinterpreted as 128x32 f32), then 128B-aligned float4 stores.
// Targets WRITE_SIZE 48MB -> ~16MB ideal (partial-line write amplification)
// and cin 4x read amplification.

typedef short bf16x8 __attribute__((ext_vector_type(8)));   // 8 bf16 (4 VGPRs)
typedef float f32x4  __attribute__((ext_vector_type(4)));

__device__ __forceinline__ unsigned pkcvt(float a, float b) {
#if defined(__has_builtin) && __has_builtin(__builtin_amdgcn_cvt_pk_bf16_f32)
  typedef __bf16 bf16x2_t __attribute__((ext_vector_type(2)));
  bf16x2_t r = __builtin_amdgcn_cvt_pk_bf16_f32(a, b);
  union { bf16x2_t v; unsigned u; } cv; cv.v = r;
  return cv.u;
#else
  unsigned ua = __float_as_uint(a), ub = __float_as_uint(b);
  ua = (ua + 0x7fffu + ((ua >> 16) & 1u)) >> 16;
  ub = (ub + 0x7fffu + ((ub >> 16) & 1u)) & 0xffff0000u;
  return ua | ub;
#endif
}

union pk8 { unsigned u[4]; bf16x8 v; };

__device__ __forceinline__ void gl_lds16(const void* g, void* l) {
  __builtin_amdgcn_global_load_lds(
      (const __attribute__((address_space(1))) unsigned*)g,
      (__attribute__((address_space(3))) unsigned*)l, 16, 0, 0);
}

// ---------- merged prep: W transpose (blocks 0..2047) + xh convert (2048..4095) ----------
// W part: tile = 64 u x 4 gates x 64 k per block. Output wsB[n*4096 + c][k]
// bf16, c = 4*u + gate, with 16B chunk pc of each 64k-window holding logical
// chunk pc ^ (c&7)  (pre-swizzle contract of lstm_mm, unchanged).
__global__ __launch_bounds__(256)
void prep_all(const float* __restrict__ x, const float* __restrict__ h,
              const float* __restrict__ W, void* wsAv, void* wsBv)
{
  __shared__ short Ls[64 * 258];   // 64 k-rows x (4 gates * 64 u + 2 pad) = 33 KB
  const int t   = threadIdx.x;
  const int bid = blockIdx.x;

  if (bid < 2048) {
    // ---- W transpose ----
    const int utile = bid & 15;              // 16 u-tiles of 64
    const int ktile = (bid >> 4) & 63;       // 64 k-tiles of 64
    const int n     = bid >> 10;             // 2 n-splits
    const int u0    = utile * 64;
    const int k0    = ktile * 64;
    const int kq    = k0 >> 11;              // k-tile lies in one kq slab
    const int krow0 = k0 & 2047;

    // phase 1: wave = gate; per instr 4 k-rows x 256B contiguous float4 spans.
    // FULL unroll: 16 loads in flight (latency-bound otherwise).
    const int g    = t >> 6;                 // gate = wave id
    const int l15  = t & 15;                 // u within segment (x4 floats)
    const int rsel = (t >> 4) & 3;           // k-row within quad
    const float* wbase = W + ((size_t)(kq * 2 + n) * 2048 + krow0) * 4096
                           + g * 1024 + u0 + l15 * 4;
    #pragma unroll
    for (int i = 0; i < 16; ++i) {
      const int kk = i * 4 + rsel;           // 0..63
      const float4 v = *(const float4*)(wbase + (size_t)kk * 4096);
      const int ad = kk * 258 + g * 64 + l15 * 4;   // de-interleaved row layout
      *(unsigned*)&Ls[ad]     = pkcvt(v.x, v.y);
      *(unsigned*)&Ls[ad + 2] = pkcvt(v.z, v.w);
    }
    __syncthreads();

    // phase 2: gather 8 k-consecutive bf16 per 16B chunk; wave stores
    // 8 full 128B rows per instr (fully coalesced), chunk-XOR pre-swizzled.
    const int cg = t >> 3;                   // 0..31 c-group
    const int pc = t & 7;                    // physical chunk
    char* outb = (char*)wsBv + (size_t)(n * 4096 + u0 * 4) * 8192
               + (size_t)k0 * 2 + pc * 16;
    #pragma unroll
    for (int j2 = 0; j2 < 8; ++j2) {
      const int c_l  = j2 * 32 + cg;         // 0..255 within tile
      const int gg   = c_l & 3;
      const int uloc = c_l >> 2;
      const int lc   = pc ^ (c_l & 7);       // logical chunk (swizzle contract)
      const int base = lc * 8 * 258 + gg * 64 + uloc;
      pk8 o;
      #pragma unroll
      for (int q = 0; q < 4; ++q) {
        const unsigned s0 = (unsigned short)Ls[base + (2 * q)     * 258];
        const unsigned s1 = (unsigned short)Ls[base + (2 * q + 1) * 258];
        o.u[q] = s0 | (s1 << 16);
      }
      *(bf16x8*)(outb + (size_t)c_l * 8192) = o.v;
    }
  } else {
    // ---- xh -> bf16 wsA[row][k], chunk pre-XORed by row&7 (unchanged) ----
    const int gid = (bid - 2048) * 256 + t;  // 524288 total
    const int row = gid >> 9;
    const int r9  = gid & 511;
    const int kt  = r9 >> 3;
    const int pcx = r9 & 7;
    const int lcx = pcx ^ (row & 7);
    const int kk0 = kt * 64 + lcx * 8;
    const int blk = kk0 >> 10;               // 0..3 -> x0,h0,x1,h1
    const float* src = ((blk & 1) ? h : x) + row * 2048 + (blk >> 1) * 1024 + (kk0 & 1023);
    const float4 p0 = ((const float4*)src)[0];
    const float4 p1 = ((const float4*)src)[1];
    pk8 o;
    o.u[0] = pkcvt(p0.x, p0.y); o.u[1] = pkcvt(p0.z, p0.w);
    o.u[2] = pkcvt(p1.x, p1.y); o.u[3] = pkcvt(p1.z, p1.w);
    *(bf16x8*)((char*)wsAv + (size_t)row * 8192 + kt * 128 + pcx * 16) = o.v;
  }
}

// ---------- main: m97-structure GEMM (R1 loop) + LDS-bounce epilogue ----------
__global__ __launch_bounds__(256, 3)
void lstm_mm(const void* wsAv, const void* wsBv,
             const float* __restrict__ cin, float* __restrict__ out)
{
  __shared__ short As[128 * 64];    // 16 KB; reused as hL (128x32 f32) in epilogue
  __shared__ short Bs[128 * 64];    // 16 KB; reused as cL
  __shared__ float CinL[128 * 32];  // 16 KB coalesced cin stage

  const int tid  = threadIdx.x;
  const int lane = tid & 63;
  const int wid  = tid >> 6;
  const int wr   = wid >> 1;
  const int wc   = wid & 1;

  const int bid     = blockIdx.x;                 // 512 = 8 rowblk x 64 colblk
  const int rowblk  = bid >> 6;                   // bid%8==colblk%8 -> XCD share
  const int colblk  = bid & 63;
  const int n       = colblk >> 5;
  const int u0      = (colblk & 31) * 32;
  const int rowbase = rowblk * 128;

  const int am   = lane & 15;
  const int quad = lane >> 4;
  const int rA   = lane >> 3;                     // row within 8-row group
  const int pcA  = lane & 7;

  const char* wsA = (const char*)wsAv;
  const char* wsB = (const char*)wsBv;
  const size_t aRowBase = (size_t)(rowbase + wid * 32) * 8192;
  const size_t bRowBase = (size_t)(n * 4096 + 4 * u0 + wid * 32) * 8192;

  f32x4 acc[4][4];
  const f32x4 zero = {0.f, 0.f, 0.f, 0.f};
  #pragma unroll
  for (int i = 0; i < 4; ++i)
    #pragma unroll
    for (int j = 0; j < 4; ++j) acc[i][j] = zero;

  for (int kt = 0; kt < 64; ++kt) {
    __syncthreads();   // previous iter's ds_reads done before overwrite
    #pragma unroll
    for (int q = 0; q < 4; ++q) {
      // each instr: 64 lanes x 16B = 8 rows x 128B, LDS dest wave-uniform
      gl_lds16(wsA + aRowBase + (size_t)(q * 8 + rA) * 8192 + kt * 128 + pcA * 16,
               &As[(wid * 32 + q * 8) * 64]);
      gl_lds16(wsB + bRowBase + (size_t)(q * 8 + rA) * 8192 + kt * 128 + pcA * 16,
               &Bs[(wid * 32 + q * 8) * 64]);
    }
    __syncthreads();   // vmcnt(0) drain -> data visible

    #pragma unroll
    for (int s = 0; s < 2; ++s) {
      const int sw = ((s * 4 + quad) ^ (am & 7)) * 8;   // zero-conflict (verified)
      bf16x8 af[4], bfr[4];
      #pragma unroll
      for (int tm = 0; tm < 4; ++tm)
        af[tm] = *(const bf16x8*)&As[(wr * 64 + tm * 16 + am) * 64 + sw];
      #pragma unroll
      for (int tn = 0; tn < 4; ++tn)
        bfr[tn] = *(const bf16x8*)&Bs[(wc * 64 + tn * 16 + am) * 64 + sw];
      #pragma unroll
      for (int tm = 0; tm < 4; ++tm)
        #pragma unroll
        for (int tn = 0; tn < 4; ++tn)
          acc[tm][tn] = __builtin_amdgcn_mfma_f32_16x16x32_bf16(
              af[tm], bfr[tn], acc[tm][tn], 0, 0, 0);
    }
  }

  // ---- epilogue: coalesced cin stage, in-register gates, LDS-bounce stores ----
  const int BU = 1024 * 2048;
  const int ob = n * 1024 + u0;

  // cin -> CinL, fully coalesced (128B-aligned float4 runs). Independent LDS
  // region, so no ordering needed vs As/Bs until the barrier below.
  float4 cv[4];
  #pragma unroll
  for (int i = 0; i < 4; ++i) {
    const int idx = i * 256 + tid;
    const int row = idx >> 3, c4 = idx & 7;
    cv[i] = *(const float4*)&cin[(size_t)(rowbase + row) * 2048 + ob + c4 * 4];
  }
  #pragma unroll
  for (int i = 0; i < 4; ++i) ((float4*)CinL)[i * 256 + tid] = cv[i];
  __syncthreads();   // (a) all waves' final ds_reads of As/Bs done; (b) CinL ready

  float* hL = (float*)As;   // 128 rows x 32 u-cols
  float* cL = (float*)Bs;

  const int g    = lane & 3;
  const int base = lane & ~3;
  #pragma unroll
  for (int tn = 0; tn < 4; ++tn) {
    const int cloc = (wc * 64 + tn * 16 + am) >> 2;   // 0..31, same for 4-lane group
    #pragma unroll
    for (int tm = 0; tm < 4; ++tm) {
      const int r0 = wr * 64 + tm * 16 + quad * 4;    // 0..127 local row
      #pragma unroll
      for (int r = 0; r < 4; ++r) {
        const float val = acc[tm][tn][r];
        const float xs  = (g == 2) ? 2.f * val : val;       // tanh via sigmoid
        const float sg  = 1.f / (1.f + __expf(-xs));
        const float act = (g == 2) ? (2.f * sg - 1.f) : sg;
        const float ig = __shfl(act, base + 0, 64);
        const float fg = __shfl(act, base + 1, 64);
        const float gg = __shfl(act, base + 2, 64);
        const float og = __shfl(act, base + 3, 64);
        const float cold = CinL[(r0 + r) * 32 + cloc];      // LDS broadcast
        const float nc = fg * cold + ig * gg;
        const float th = 1.f - 2.f / (1.f + __expf(2.f * nc));
        const float nh = og * th;
        if (g == 0) hL[(r0 + r) * 32 + cloc] = nh;
        if (g == 1) cL[(r0 + r) * 32 + cloc] = nc;
      }
    }
  }
  __syncthreads();

  // coalesced stores: per wave-instr 64 lanes x 16B = 8 rows x 128B aligned runs
  #pragma unroll
  for (int i = 0; i < 4; ++i) {
    const int idx = i * 256 + tid;
    const int row = idx >> 3, c4 = idx & 7;
    const size_t go = (size_t)(rowbase + row) * 2048 + ob + c4 * 4;
    *(float4*)&out[go]      = ((float4*)hL)[idx];
    *(float4*)&out[BU + go] = ((float4*)cL)[idx];
  }
}

// ---------- fallback: round-4 fused kernel (used when ws too small) ----------
__global__ __launch_bounds__(512, 4)
void lstm_fused_fb(const float* __restrict__ x, const float* __restrict__ h,
                   const float* __restrict__ cin, const float* __restrict__ W,
                   float* __restrict__ out)
{
  __shared__ short As[128 * 64];
  __shared__ short Bs[128 * 64];
  const int tid  = threadIdx.x;
  const int lane = tid & 63;
  const int wid  = tid >> 6;
  const int wr   = wid >> 2;
  const int wq   = wid & 3;
  const int bid     = blockIdx.x;
  const int rowblk  = bid >> 6;
  const int colblk  = bid & 63;
  const int n       = colblk >> 5;
  const int u0      = (colblk & 31) * 32;
  const int rowbase = rowblk * 128;
  const int ar = tid >> 2;
  const int aq = tid & 3;
  const int bc   = tid & 127;
  const int bgt  = bc & 3;
  const int bu   = bc >> 2;
  const int kgrp = tid >> 7;
  const int gcol = bgt * 1024 + u0 + bu;
  const int am   = lane & 15;
  const int quad = lane >> 4;

  f32x4 acc[4][2];
  const f32x4 zero = {0.f, 0.f, 0.f, 0.f};
  #pragma unroll
  for (int i = 0; i < 4; ++i)
    #pragma unroll
    for (int j = 0; j < 2; ++j) acc[i][j] = zero;

  float4 areg[4];
  float  breg[16];
  auto load_tiles = [&](int kt) {
    const int blk = kt >> 4;
    const float* asrc = (blk & 1) ? h : x;
    const int cb = (blk >> 1) * 1024 + (kt & 15) * 64;
    const float4* p = (const float4*)(asrc + (rowbase + ar) * 2048 + cb + aq * 16);
    #pragma unroll
    for (int q = 0; q < 4; ++q) areg[q] = p[q];
    const int kq = kt >> 5;
    const float* wp = W + ((kq * 2 + n) * 2048 + (kt & 31) * 64 + kgrp * 16) * 4096 + gcol;
    #pragma unroll
    for (int j = 0; j < 16; ++j) breg[j] = wp[j * 4096];
  };
  load_tiles(0);
  for (int kt = 0; kt < 64; ++kt) {
    bf16x8 aw[2];
    {
      pk8 p0, p1;
      p0.u[0] = pkcvt(areg[0].x, areg[0].y); p0.u[1] = pkcvt(areg[0].z, areg[0].w);
      p0.u[2] = pkcvt(areg[1].x, areg[1].y); p0.u[3] = pkcvt(areg[1].z, areg[1].w);
      p1.u[0] = pkcvt(areg[2].x, areg[2].y); p1.u[1] = pkcvt(areg[2].z, areg[2].w);
      p1.u[2] = pkcvt(areg[3].x, areg[3].y); p1.u[3] = pkcvt(areg[3].z, areg[3].w);
      aw[0] = p0.v; aw[1] = p1.v;
    }
    bf16x8 bw[2];
    {
      pk8 q0, q1;
      #pragma unroll
      for (int j = 0; j < 4; ++j) {
        q0.u[j] = pkcvt(breg[2 * j],     breg[2 * j + 1]);
        q1.u[j] = pkcvt(breg[8 + 2 * j], breg[8 + 2 * j + 1]);
      }
      bw[0] = q0.v; bw[1] = q1.v;
    }
    __syncthreads();
    #pragma unroll
    for (int hh = 0; hh < 2; ++hh)
      *(bf16x8*)&As[ar * 64 + (((aq * 2 + hh) ^ (ar & 7)) * 8)] = aw[hh];
    #pragma unroll
    for (int hh = 0; hh < 2; ++hh)
      *(bf16x8*)&Bs[bc * 64 + (((kgrp * 2 + hh) ^ (bc & 7)) * 8)] = bw[hh];
    __syncthreads();
    if (kt < 63) load_tiles(kt + 1);
    #pragma unroll
    for (int s = 0; s < 2; ++s) {
      const int sw = ((s * 4 + quad) ^ (am & 7)) * 8;
      bf16x8 af[4], bfr[2];
      #pragma unroll
      for (int tm = 0; tm < 4; ++tm)
        af[tm] = *(const bf16x8*)&As[(wr * 64 + tm * 16 + am) * 64 + sw];
      #pragma unroll
      for (int tn = 0; tn < 2; ++tn)
        bfr[tn] = *(const bf16x8*)&Bs[(wq * 32 + tn * 16 + am) * 64 + sw];
      #pragma unroll
      for (int tm = 0; tm < 4; ++tm)
        #pragma unroll
        for (int tn = 0; tn < 2; ++tn)
          acc[tm][tn] = __builtin_amdgcn_mfma_f32_16x16x32_bf16(
              af[tm], bfr[tn], acc[tm][tn], 0, 0, 0);
    }
  }
  const int BU   = 1024 * 2048;
  const int g    = lane & 3;
  const int base = lane & ~3;
  #pragma unroll
  for (int tn = 0; tn < 2; ++tn) {
    const int cil = wq * 32 + tn * 16 + am;
    const int col = n * 1024 + u0 + (cil >> 2);
    #pragma unroll
    for (int tm = 0; tm < 4; ++tm) {
      const int brow0 = rowbase + wr * 64 + tm * 16 + quad * 4;
      #pragma unroll
      for (int r = 0; r < 4; ++r) {
        const int brow = brow0 + r;
        const float val = acc[tm][tn][r];
        const float xs  = (g == 2) ? 2.f * val : val;
        const float sg  = 1.f / (1.f + __expf(-xs));
        const float act = (g == 2) ? (2.f * sg - 1.f) : sg;
        const float ig = __shfl(act, base + 0, 64);
        const float fg = __shfl(act, base + 1, 64);
        const float gg = __shfl(act, base + 2, 64);
        const float og = __shfl(act, base + 3, 64);
        const float cold = cin[brow * 2048 + col];
        const float nc = fg * cold + ig * gg;
        const float th = 1.f - 2.f / (1.f + __expf(2.f * nc));
        const float nh = og * th;
        if (g == 0) out[brow * 2048 + col]      = nh;
        if (g == 1) out[BU + brow * 2048 + col] = nc;
      }
    }
  }
}

extern "C" void kernel_launch(void* const* d_in, const int* in_sizes, int n_in,
                              void* d_out, int out_size, void* d_ws, size_t ws_size,
                              hipStream_t stream) {
  const float* x = (const float*)d_in[0];
  const float* h = (const float*)d_in[1];
  const float* c = (const float*)d_in[2];
  const float* W = (const float*)d_in[3];
  float* out = (float*)d_out;

  const size_t WSA_BYTES = (size_t)1024 * 4096 * 2;        //  8 MB bf16 xh
  const size_t WSB_BYTES = (size_t)2 * 4096 * 4096 * 2;    // 67 MB bf16 W^T
  if (ws_size >= WSA_BYTES + WSB_BYTES) {
    char* wsA = (char*)d_ws;
    char* wsB = (char*)d_ws + WSA_BYTES;
    // blocks 0..2047: W transpose (long pole, dispatched first);
    // blocks 2048..4095: xh convert (backfills, overlaps the W stream).
    prep_all<<<dim3(4096), dim3(256), 0, stream>>>(x, h, W, wsA, wsB);
    lstm_mm<<<dim3(512), dim3(256), 0, stream>>>(wsA, wsB, c, out);
  } else {
    lstm_fused_fb<<<dim3(512), dim3(512), 0, stream>>>(x, h, c, W, out);
  }
}

// Round 5
// 300.337 us; speedup vs baseline: 1.0510x; 1.0051x over previous
//
#include <hip/hip_runtime.h>
#include <hip/hip_bf16.h>

// LSTMCell fused: ifgo = [x0 h0 x1 h1] @ W  (M=1024, N=8192, K=4096) + gates.
// Round 10: mm K-loop restructured "read-first, stage-late" (single buffer):
//   for kt: ds_read ALL 16 frags -> regs; __syncthreads (LDS dead);
//           stage(kt+1) into same LDS; 32 MFMA from regs; __syncthreads (drain).
// The vmcnt(0) drain at the trailing barrier now overlaps the MFMA phase
// instead of stalling cold (R4: MfmaUtil 32%, HBM 12% -> drain-bound at 88us).
// Unlike R2's dbuf (regressed: compiler vmcnt(0) before ds_read due to LDS
// aliasing), reads precede loads in program order -> no alias hazard.
// Epilogue LDS bounce (R4-verified: WRITE 48->16.4MB), prep_all, swizzle
// contract all unchanged.

typedef short bf16x8 __attribute__((ext_vector_type(8)));   // 8 bf16 (4 VGPRs)
typedef float f32x4  __attribute__((ext_vector_type(4)));

__device__ __forceinline__ unsigned pkcvt(float a, float b) {
#if defined(__has_builtin) && __has_builtin(__builtin_amdgcn_cvt_pk_bf16_f32)
  typedef __bf16 bf16x2_t __attribute__((ext_vector_type(2)));
  bf16x2_t r = __builtin_amdgcn_cvt_pk_bf16_f32(a, b);
  union { bf16x2_t v; unsigned u; } cv; cv.v = r;
  return cv.u;
#else
  unsigned ua = __float_as_uint(a), ub = __float_as_uint(b);
  ua = (ua + 0x7fffu + ((ua >> 16) & 1u)) >> 16;
  ub = (ub + 0x7fffu + ((ub >> 16) & 1u)) & 0xffff0000u;
  return ua | ub;
#endif
}

union pk8 { unsigned u[4]; bf16x8 v; };

__device__ __forceinline__ void gl_lds16(const void* g, void* l) {
  __builtin_amdgcn_global_load_lds(
      (const __attribute__((address_space(1))) unsigned*)g,
      (__attribute__((address_space(3))) unsigned*)l, 16, 0, 0);
}

// ---------- merged prep: W transpose (blocks 0..2047) + xh convert (2048..4095) ----------
// W part: tile = 64 u x 4 gates x 64 k per block. Output wsB[n*4096 + c][k]
// bf16, c = 4*u + gate, with 16B chunk pc of each 64k-window holding logical
// chunk pc ^ (c&7)  (pre-swizzle contract of lstm_mm, unchanged).
__global__ __launch_bounds__(256)
void prep_all(const float* __restrict__ x, const float* __restrict__ h,
              const float* __restrict__ W, void* wsAv, void* wsBv)
{
  __shared__ short Ls[64 * 258];   // 64 k-rows x (4 gates * 64 u + 2 pad) = 33 KB
  const int t   = threadIdx.x;
  const int bid = blockIdx.x;

  if (bid < 2048) {
    // ---- W transpose ----
    const int utile = bid & 15;              // 16 u-tiles of 64
    const int ktile = (bid >> 4) & 63;       // 64 k-tiles of 64
    const int n     = bid >> 10;             // 2 n-splits
    const int u0    = utile * 64;
    const int k0    = ktile * 64;
    const int kq    = k0 >> 11;              // k-tile lies in one kq slab
    const int krow0 = k0 & 2047;

    // phase 1: wave = gate; per instr 4 k-rows x 256B contiguous float4 spans.
    // FULL unroll: 16 loads in flight (latency-bound otherwise).
    const int g    = t >> 6;                 // gate = wave id
    const int l15  = t & 15;                 // u within segment (x4 floats)
    const int rsel = (t >> 4) & 3;           // k-row within quad
    const float* wbase = W + ((size_t)(kq * 2 + n) * 2048 + krow0) * 4096
                           + g * 1024 + u0 + l15 * 4;
    #pragma unroll
    for (int i = 0; i < 16; ++i) {
      const int kk = i * 4 + rsel;           // 0..63
      const float4 v = *(const float4*)(wbase + (size_t)kk * 4096);
      const int ad = kk * 258 + g * 64 + l15 * 4;   // de-interleaved row layout
      *(unsigned*)&Ls[ad]     = pkcvt(v.x, v.y);
      *(unsigned*)&Ls[ad + 2] = pkcvt(v.z, v.w);
    }
    __syncthreads();

    // phase 2: gather 8 k-consecutive bf16 per 16B chunk; wave stores
    // 8 full 128B rows per instr (fully coalesced), chunk-XOR pre-swizzled.
    const int cg = t >> 3;                   // 0..31 c-group
    const int pc = t & 7;                    // physical chunk
    char* outb = (char*)wsBv + (size_t)(n * 4096 + u0 * 4) * 8192
               + (size_t)k0 * 2 + pc * 16;
    #pragma unroll
    for (int j2 = 0; j2 < 8; ++j2) {
      const int c_l  = j2 * 32 + cg;         // 0..255 within tile
      const int gg   = c_l & 3;
      const int uloc = c_l >> 2;
      const int lc   = pc ^ (c_l & 7);       // logical chunk (swizzle contract)
      const int base = lc * 8 * 258 + gg * 64 + uloc;
      pk8 o;
      #pragma unroll
      for (int q = 0; q < 4; ++q) {
        const unsigned s0 = (unsigned short)Ls[base + (2 * q)     * 258];
        const unsigned s1 = (unsigned short)Ls[base + (2 * q + 1) * 258];
        o.u[q] = s0 | (s1 << 16);
      }
      *(bf16x8*)(outb + (size_t)c_l * 8192) = o.v;
    }
  } else {
    // ---- xh -> bf16 wsA[row][k], chunk pre-XORed by row&7 (unchanged) ----
    const int gid = (bid - 2048) * 256 + t;  // 524288 total
    const int row = gid >> 9;
    const int r9  = gid & 511;
    const int kt  = r9 >> 3;
    const int pcx = r9 & 7;
    const int lcx = pcx ^ (row & 7);
    const int kk0 = kt * 64 + lcx * 8;
    const int blk = kk0 >> 10;               // 0..3 -> x0,h0,x1,h1
    const float* src = ((blk & 1) ? h : x) + row * 2048 + (blk >> 1) * 1024 + (kk0 & 1023);
    const float4 p0 = ((const float4*)src)[0];
    const float4 p1 = ((const float4*)src)[1];
    pk8 o;
    o.u[0] = pkcvt(p0.x, p0.y); o.u[1] = pkcvt(p0.z, p0.w);
    o.u[2] = pkcvt(p1.x, p1.y); o.u[3] = pkcvt(p1.z, p1.w);
    *(bf16x8*)((char*)wsAv + (size_t)row * 8192 + kt * 128 + pcx * 16) = o.v;
  }
}

// ---------- main: m97-structure GEMM, read-first/stage-late + LDS-bounce epilogue ----------
__global__ __launch_bounds__(256, 2)
void lstm_mm(const void* wsAv, const void* wsBv,
             const float* __restrict__ cin, float* __restrict__ out)
{
  __shared__ short As[128 * 64];    // 16 KB; reused as hL (128x32 f32) in epilogue
  __shared__ short Bs[128 * 64];    // 16 KB; reused as cL
  __shared__ float CinL[128 * 32];  // 16 KB coalesced cin stage

  const int tid  = threadIdx.x;
  const int lane = tid & 63;
  const int wid  = tid >> 6;
  const int wr   = wid >> 1;
  const int wc   = wid & 1;

  const int bid     = blockIdx.x;                 // 512 = 8 rowblk x 64 colblk
  const int rowblk  = bid >> 6;                   // bid%8==colblk%8 -> XCD share
  const int colblk  = bid & 63;
  const int n       = colblk >> 5;
  const int u0      = (colblk & 31) * 32;
  const int rowbase = rowblk * 128;

  const int am   = lane & 15;
  const int quad = lane >> 4;
  const int rA   = lane >> 3;                     // row within 8-row group
  const int pcA  = lane & 7;

  const char* wsA = (const char*)wsAv;
  const char* wsB = (const char*)wsBv;
  const size_t aRowBase = (size_t)(rowbase + wid * 32) * 8192;
  const size_t bRowBase = (size_t)(n * 4096 + 4 * u0 + wid * 32) * 8192;

  f32x4 acc[4][4];
  const f32x4 zero = {0.f, 0.f, 0.f, 0.f};
  #pragma unroll
  for (int i = 0; i < 4; ++i)
    #pragma unroll
    for (int j = 0; j < 4; ++j) acc[i][j] = zero;

  // stage K-tile kt (each instr: 64 lanes x 16B = 8 rows x 128B, LDS dest
  // wave-uniform; source pre-swizzled so linear copy lands right).
  auto stage = [&](int kt) {
    #pragma unroll
    for (int q = 0; q < 4; ++q) {
      gl_lds16(wsA + aRowBase + (size_t)(q * 8 + rA) * 8192 + kt * 128 + pcA * 16,
               &As[(wid * 32 + q * 8) * 64]);
      gl_lds16(wsB + bRowBase + (size_t)(q * 8 + rA) * 8192 + kt * 128 + pcA * 16,
               &Bs[(wid * 32 + q * 8) * 64]);
    }
  };

  stage(0);
  __syncthreads();                 // tile 0 resident

  for (int kt = 0; kt < 64; ++kt) {
    // 1) pull ALL fragments of this tile into registers (compile-time indexed)
    bf16x8 af2[2][4], bf2[2][4];
    #pragma unroll
    for (int s = 0; s < 2; ++s) {
      const int sw = ((s * 4 + quad) ^ (am & 7)) * 8;   // zero-conflict (verified)
      #pragma unroll
      for (int tm = 0; tm < 4; ++tm)
        af2[s][tm] = *(const bf16x8*)&As[(wr * 64 + tm * 16 + am) * 64 + sw];
      #pragma unroll
      for (int tn = 0; tn < 4; ++tn)
        bf2[s][tn] = *(const bf16x8*)&Bs[(wc * 64 + tn * 16 + am) * 64 + sw];
    }
    __syncthreads();   // lgkm drained: frags in regs, LDS free to overwrite

    // 2) issue next tile's staging EARLY -- latency hides under MFMAs below
    if (kt < 63) stage(kt + 1);

    // 3) MFMAs from registers
    #pragma unroll
    for (int s = 0; s < 2; ++s)
      #pragma unroll
      for (int tm = 0; tm < 4; ++tm)
        #pragma unroll
        for (int tn = 0; tn < 4; ++tn)
          acc[tm][tn] = __builtin_amdgcn_mfma_f32_16x16x32_bf16(
              af2[s][tm], bf2[s][tn], acc[tm][tn], 0, 0, 0);

    // 4) drain staging (vmcnt(0) here overlapped with the MFMA phase)
    __syncthreads();
  }

  // ---- epilogue: coalesced cin stage, in-register gates, LDS-bounce stores ----
  const int BU = 1024 * 2048;
  const int ob = n * 1024 + u0;

  // cin -> CinL, fully coalesced (128B-aligned float4 runs). Independent LDS
  // region, so no ordering needed vs As/Bs until the barrier below.
  float4 cv[4];
  #pragma unroll
  for (int i = 0; i < 4; ++i) {
    const int idx = i * 256 + tid;
    const int row = idx >> 3, c4 = idx & 7;
    cv[i] = *(const float4*)&cin[(size_t)(rowbase + row) * 2048 + ob + c4 * 4];
  }
  #pragma unroll
  for (int i = 0; i < 4; ++i) ((float4*)CinL)[i * 256 + tid] = cv[i];
  __syncthreads();   // (a) all waves past K-loop; (b) CinL ready

  float* hL = (float*)As;   // 128 rows x 32 u-cols
  float* cL = (float*)Bs;

  const int g    = lane & 3;
  const int base = lane & ~3;
  #pragma unroll
  for (int tn = 0; tn < 4; ++tn) {
    const int cloc = (wc * 64 + tn * 16 + am) >> 2;   // 0..31, same for 4-lane group
    #pragma unroll
    for (int tm = 0; tm < 4; ++tm) {
      const int r0 = wr * 64 + tm * 16 + quad * 4;    // 0..127 local row
      #pragma unroll
      for (int r = 0; r < 4; ++r) {
        const float val = acc[tm][tn][r];
        const float xs  = (g == 2) ? 2.f * val : val;       // tanh via sigmoid
        const float sg  = 1.f / (1.f + __expf(-xs));
        const float act = (g == 2) ? (2.f * sg - 1.f) : sg;
        const float ig = __shfl(act, base + 0, 64);
        const float fg = __shfl(act, base + 1, 64);
        const float gg = __shfl(act, base + 2, 64);
        const float og = __shfl(act, base + 3, 64);
        const float cold = CinL[(r0 + r) * 32 + cloc];      // LDS broadcast
        const float nc = fg * cold + ig * gg;
        const float th = 1.f - 2.f / (1.f + __expf(2.f * nc));
        const float nh = og * th;
        if (g == 0) hL[(r0 + r) * 32 + cloc] = nh;
        if (g == 1) cL[(r0 + r) * 32 + cloc] = nc;
      }
    }
  }
  __syncthreads();

  // coalesced stores: per wave-instr 64 lanes x 16B = 8 rows x 128B aligned runs
  #pragma unroll
  for (int i = 0; i < 4; ++i) {
    const int idx = i * 256 + tid;
    const int row = idx >> 3, c4 = idx & 7;
    const size_t go = (size_t)(rowbase + row) * 2048 + ob + c4 * 4;
    *(float4*)&out[go]      = ((float4*)hL)[idx];
    *(float4*)&out[BU + go] = ((float4*)cL)[idx];
  }
}

// ---------- fallback: round-4 fused kernel (used when ws too small) ----------
__global__ __launch_bounds__(512, 4)
void lstm_fused_fb(const float* __restrict__ x, const float* __restrict__ h,
                   const float* __restrict__ cin, const float* __restrict__ W,
                   float* __restrict__ out)
{
  __shared__ short As[128 * 64];
  __shared__ short Bs[128 * 64];
  const int tid  = threadIdx.x;
  const int lane = tid & 63;
  const int wid  = tid >> 6;
  const int wr   = wid >> 2;
  const int wq   = wid & 3;
  const int bid     = blockIdx.x;
  const int rowblk  = bid >> 6;
  const int colblk  = bid & 63;
  const int n       = colblk >> 5;
  const int u0      = (colblk & 31) * 32;
  const int rowbase = rowblk * 128;
  const int ar = tid >> 2;
  const int aq = tid & 3;
  const int bc   = tid & 127;
  const int bgt  = bc & 3;
  const int bu   = bc >> 2;
  const int kgrp = tid >> 7;
  const int gcol = bgt * 1024 + u0 + bu;
  const int am   = lane & 15;
  const int quad = lane >> 4;

  f32x4 acc[4][2];
  const f32x4 zero = {0.f, 0.f, 0.f, 0.f};
  #pragma unroll
  for (int i = 0; i < 4; ++i)
    #pragma unroll
    for (int j = 0; j < 2; ++j) acc[i][j] = zero;

  float4 areg[4];
  float  breg[16];
  auto load_tiles = [&](int kt) {
    const int blk = kt >> 4;
    const float* asrc = (blk & 1) ? h : x;
    const int cb = (blk >> 1) * 1024 + (kt & 15) * 64;
    const float4* p = (const float4*)(asrc + (rowbase + ar) * 2048 + cb + aq * 16);
    #pragma unroll
    for (int q = 0; q < 4; ++q) areg[q] = p[q];
    const int kq = kt >> 5;
    const float* wp = W + ((kq * 2 + n) * 2048 + (kt & 31) * 64 + kgrp * 16) * 4096 + gcol;
    #pragma unroll
    for (int j = 0; j < 16; ++j) breg[j] = wp[j * 4096];
  };
  load_tiles(0);
  for (int kt = 0; kt < 64; ++kt) {
    bf16x8 aw[2];
    {
      pk8 p0, p1;
      p0.u[0] = pkcvt(areg[0].x, areg[0].y); p0.u[1] = pkcvt(areg[0].z, areg[0].w);
      p0.u[2] = pkcvt(areg[1].x, areg[1].y); p0.u[3] = pkcvt(areg[1].z, areg[1].w);
      p1.u[0] = pkcvt(areg[2].x, areg[2].y); p1.u[1] = pkcvt(areg[2].z, areg[2].w);
      p1.u[2] = pkcvt(areg[3].x, areg[3].y); p1.u[3] = pkcvt(areg[3].z, areg[3].w);
      aw[0] = p0.v; aw[1] = p1.v;
    }
    bf16x8 bw[2];
    {
      pk8 q0, q1;
      #pragma unroll
      for (int j = 0; j < 4; ++j) {
        q0.u[j] = pkcvt(breg[2 * j],     breg[2 * j + 1]);
        q1.u[j] = pkcvt(breg[8 + 2 * j], breg[8 + 2 * j + 1]);
      }
      bw[0] = q0.v; bw[1] = q1.v;
    }
    __syncthreads();
    #pragma unroll
    for (int hh = 0; hh < 2; ++hh)
      *(bf16x8*)&As[ar * 64 + (((aq * 2 + hh) ^ (ar & 7)) * 8)] = aw[hh];
    #pragma unroll
    for (int hh = 0; hh < 2; ++hh)
      *(bf16x8*)&Bs[bc * 64 + (((kgrp * 2 + hh) ^ (bc & 7)) * 8)] = bw[hh];
    __syncthreads();
    if (kt < 63) load_tiles(kt + 1);
    #pragma unroll
    for (int s = 0; s < 2; ++s) {
      const int sw = ((s * 4 + quad) ^ (am & 7)) * 8;
      bf16x8 af[4], bfr[2];
      #pragma unroll
      for (int tm = 0; tm < 4; ++tm)
        af[tm] = *(const bf16x8*)&As[(wr * 64 + tm * 16 + am) * 64 + sw];
      #pragma unroll
      for (int tn = 0; tn < 2; ++tn)
        bfr[tn] = *(const bf16x8*)&Bs[(wq * 32 + tn * 16 + am) * 64 + sw];
      #pragma unroll
      for (int tm = 0; tm < 4; ++tm)
        #pragma unroll
        for (int tn = 0; tn < 2; ++tn)
          acc[tm][tn] = __builtin_amdgcn_mfma_f32_16x16x32_bf16(
              af[tm], bfr[tn], acc[tm][tn], 0, 0, 0);
    }
  }
  const int BU   = 1024 * 2048;
  const int g    = lane & 3;
  const int base = lane & ~3;
  #pragma unroll
  for (int tn = 0; tn < 2; ++tn) {
    const int cil = wq * 32 + tn * 16 + am;
    const int col = n * 1024 + u0 + (cil >> 2);
    #pragma unroll
    for (int tm = 0; tm < 4; ++tm) {
      const int brow0 = rowbase + wr * 64 + tm * 16 + quad * 4;
      #pragma unroll
      for (int r = 0; r < 4; ++r) {
        const int brow = brow0 + r;
        const float val = acc[tm][tn][r];
        const float xs  = (g == 2) ? 2.f * val : val;
        const float sg  = 1.f / (1.f + __expf(-xs));
        const float act = (g == 2) ? (2.f * sg - 1.f) : sg;
        const float ig = __shfl(act, base + 0, 64);
        const float fg = __shfl(act, base + 1, 64);
        const float gg = __shfl(act, base + 2, 64);
        const float og = __shfl(act, base + 3, 64);
        const float cold = cin[brow * 2048 + col];
        const float nc = fg * cold + ig * gg;
        const float th = 1.f - 2.f / (1.f + __expf(2.f * nc));
        const float nh = og * th;
        if (g == 0) out[brow * 2048 + col]      = nh;
        if (g == 1) out[BU + brow * 2048 + col] = nc;
      }
    }
  }
}

extern "C" void kernel_launch(void* const* d_in, const int* in_sizes, int n_in,
                              void* d_out, int out_size, void* d_ws, size_t ws_size,
                              hipStream_t stream) {
  const float* x = (const float*)d_in[0];
  const float* h = (const float*)d_in[1];
  const float* c = (const float*)d_in[2];
  const float* W = (const float*)d_in[3];
  float* out = (float*)d_out;

  const size_t WSA_BYTES = (size_t)1024 * 4096 * 2;        //  8 MB bf16 xh
  const size_t WSB_BYTES = (size_t)2 * 4096 * 4096 * 2;    // 67 MB bf16 W^T
  if (ws_size >= WSA_BYTES + WSB_BYTES) {
    char* wsA = (char*)d_ws;
    char* wsB = (char*)d_ws + WSA_BYTES;
    // blocks 0..2047: W transpose (long pole, dispatched first);
    // blocks 2048..4095: xh convert (backfills, overlaps the W stream).
    prep_all<<<dim3(4096), dim3(256), 0, stream>>>(x, h, W, wsA, wsB);
    lstm_mm<<<dim3(512), dim3(256), 0, stream>>>(wsA, wsB, c, out);
  } else {
    lstm_fused_fb<<<dim3(512), dim3(512), 0, stream>>>(x, h, c, W, out);
  }
}

// Round 6
// 299.585 us; speedup vs baseline: 1.0537x; 1.0025x over previous
//
#include <hip/hip_runtime.h>
#include <hip/hip_bf16.h>

// LSTMCell fused: ifgo = [x0 h0 x1 h1] @ W  (M=1024, N=8192, K=4096) + gates.
// Round 11: mm K-loop -> guide-verified "minimum 2-phase" template (T3/T4):
// double-buffered LDS, per iter: ds_read(cur) -> stage(kt+1 -> cur^1) ->
// sched_barrier(0) -> 32 MFMA -> ONE __syncthreads (its vmcnt(0) drain is
// overlapped by the MFMA phase; at top-of-iter ds_read outstanding loads are
// already ZERO, so no R2-style compiler alias-vmcnt penalty; sched_barrier
// pins stage-issue before the MFMA cluster). 1 barrier/iter vs R4/R5's 2.
// LDS 80KB -> still 2 blocks/CU (grid-limited anyway). prep_all, swizzle
// contract, LDS-bounce epilogue (R4-verified WRITE 48->16.4MB) unchanged.

typedef short bf16x8 __attribute__((ext_vector_type(8)));   // 8 bf16 (4 VGPRs)
typedef float f32x4  __attribute__((ext_vector_type(4)));

__device__ __forceinline__ unsigned pkcvt(float a, float b) {
#if defined(__has_builtin) && __has_builtin(__builtin_amdgcn_cvt_pk_bf16_f32)
  typedef __bf16 bf16x2_t __attribute__((ext_vector_type(2)));
  bf16x2_t r = __builtin_amdgcn_cvt_pk_bf16_f32(a, b);
  union { bf16x2_t v; unsigned u; } cv; cv.v = r;
  return cv.u;
#else
  unsigned ua = __float_as_uint(a), ub = __float_as_uint(b);
  ua = (ua + 0x7fffu + ((ua >> 16) & 1u)) >> 16;
  ub = (ub + 0x7fffu + ((ub >> 16) & 1u)) & 0xffff0000u;
  return ua | ub;
#endif
}

union pk8 { unsigned u[4]; bf16x8 v; };

__device__ __forceinline__ void gl_lds16(const void* g, void* l) {
  __builtin_amdgcn_global_load_lds(
      (const __attribute__((address_space(1))) unsigned*)g,
      (__attribute__((address_space(3))) unsigned*)l, 16, 0, 0);
}

// ---------- merged prep: W transpose (blocks 0..2047) + xh convert (2048..4095) ----------
// W part: tile = 64 u x 4 gates x 64 k per block. Output wsB[n*4096 + c][k]
// bf16, c = 4*u + gate, with 16B chunk pc of each 64k-window holding logical
// chunk pc ^ (c&7)  (pre-swizzle contract of lstm_mm, unchanged).
__global__ __launch_bounds__(256)
void prep_all(const float* __restrict__ x, const float* __restrict__ h,
              const float* __restrict__ W, void* wsAv, void* wsBv)
{
  __shared__ short Ls[64 * 258];   // 64 k-rows x (4 gates * 64 u + 2 pad) = 33 KB
  const int t   = threadIdx.x;
  const int bid = blockIdx.x;

  if (bid < 2048) {
    // ---- W transpose ----
    const int utile = bid & 15;              // 16 u-tiles of 64
    const int ktile = (bid >> 4) & 63;       // 64 k-tiles of 64
    const int n     = bid >> 10;             // 2 n-splits
    const int u0    = utile * 64;
    const int k0    = ktile * 64;
    const int kq    = k0 >> 11;              // k-tile lies in one kq slab
    const int krow0 = k0 & 2047;

    // phase 1: wave = gate; per instr 4 k-rows x 256B contiguous float4 spans.
    // FULL unroll: 16 loads in flight (latency-bound otherwise).
    const int g    = t >> 6;                 // gate = wave id
    const int l15  = t & 15;                 // u within segment (x4 floats)
    const int rsel = (t >> 4) & 3;           // k-row within quad
    const float* wbase = W + ((size_t)(kq * 2 + n) * 2048 + krow0) * 4096
                           + g * 1024 + u0 + l15 * 4;
    #pragma unroll
    for (int i = 0; i < 16; ++i) {
      const int kk = i * 4 + rsel;           // 0..63
      const float4 v = *(const float4*)(wbase + (size_t)kk * 4096);
      const int ad = kk * 258 + g * 64 + l15 * 4;   // de-interleaved row layout
      *(unsigned*)&Ls[ad]     = pkcvt(v.x, v.y);
      *(unsigned*)&Ls[ad + 2] = pkcvt(v.z, v.w);
    }
    __syncthreads();

    // phase 2: gather 8 k-consecutive bf16 per 16B chunk; wave stores
    // 8 full 128B rows per instr (fully coalesced), chunk-XOR pre-swizzled.
    const int cg = t >> 3;                   // 0..31 c-group
    const int pc = t & 7;                    // physical chunk
    char* outb = (char*)wsBv + (size_t)(n * 4096 + u0 * 4) * 8192
               + (size_t)k0 * 2 + pc * 16;
    #pragma unroll
    for (int j2 = 0; j2 < 8; ++j2) {
      const int c_l  = j2 * 32 + cg;         // 0..255 within tile
      const int gg   = c_l & 3;
      const int uloc = c_l >> 2;
      const int lc   = pc ^ (c_l & 7);       // logical chunk (swizzle contract)
      const int base = lc * 8 * 258 + gg * 64 + uloc;
      pk8 o;
      #pragma unroll
      for (int q = 0; q < 4; ++q) {
        const unsigned s0 = (unsigned short)Ls[base + (2 * q)     * 258];
        const unsigned s1 = (unsigned short)Ls[base + (2 * q + 1) * 258];
        o.u[q] = s0 | (s1 << 16);
      }
      *(bf16x8*)(outb + (size_t)c_l * 8192) = o.v;
    }
  } else {
    // ---- xh -> bf16 wsA[row][k], chunk pre-XORed by row&7 (unchanged) ----
    const int gid = (bid - 2048) * 256 + t;  // 524288 total
    const int row = gid >> 9;
    const int r9  = gid & 511;
    const int kt  = r9 >> 3;
    const int pcx = r9 & 7;
    const int lcx = pcx ^ (row & 7);
    const int kk0 = kt * 64 + lcx * 8;
    const int blk = kk0 >> 10;               // 0..3 -> x0,h0,x1,h1
    const float* src = ((blk & 1) ? h : x) + row * 2048 + (blk >> 1) * 1024 + (kk0 & 1023);
    const float4 p0 = ((const float4*)src)[0];
    const float4 p1 = ((const float4*)src)[1];
    pk8 o;
    o.u[0] = pkcvt(p0.x, p0.y); o.u[1] = pkcvt(p0.z, p0.w);
    o.u[2] = pkcvt(p1.x, p1.y); o.u[3] = pkcvt(p1.z, p1.w);
    *(bf16x8*)((char*)wsAv + (size_t)row * 8192 + kt * 128 + pcx * 16) = o.v;
  }
}

// ---------- main: minimum-2-phase dbuf GEMM + LDS-bounce epilogue ----------
__global__ __launch_bounds__(256, 2)
void lstm_mm(const void* wsAv, const void* wsBv,
             const float* __restrict__ cin, float* __restrict__ out)
{
  __shared__ short As[2][128 * 64];   // 2 x 16 KB; As[0] reused as hL in epilogue
  __shared__ short Bs[2][128 * 64];   // 2 x 16 KB; Bs[0] reused as cL
  __shared__ float CinL[128 * 32];    // 16 KB coalesced cin stage

  const int tid  = threadIdx.x;
  const int lane = tid & 63;
  const int wid  = tid >> 6;
  const int wr   = wid >> 1;
  const int wc   = wid & 1;

  const int bid     = blockIdx.x;                 // 512 = 8 rowblk x 64 colblk
  const int rowblk  = bid >> 6;                   // bid%8==colblk%8 -> XCD share
  const int colblk  = bid & 63;
  const int n       = colblk >> 5;
  const int u0      = (colblk & 31) * 32;
  const int rowbase = rowblk * 128;

  const int am   = lane & 15;
  const int quad = lane >> 4;
  const int rA   = lane >> 3;                     // row within 8-row group
  const int pcA  = lane & 7;

  const char* wsA = (const char*)wsAv;
  const char* wsB = (const char*)wsBv;
  const size_t aRowBase = (size_t)(rowbase + wid * 32) * 8192;
  const size_t bRowBase = (size_t)(n * 4096 + 4 * u0 + wid * 32) * 8192;

  f32x4 acc[4][4];
  const f32x4 zero = {0.f, 0.f, 0.f, 0.f};
  #pragma unroll
  for (int i = 0; i < 4; ++i)
    #pragma unroll
    for (int j = 0; j < 4; ++j) acc[i][j] = zero;

  // stage K-tile kt into buffer b (each instr: 64 lanes x 16B = 8 rows x 128B,
  // LDS dest wave-uniform; source pre-swizzled so linear copy lands right).
  auto stage = [&](int kt, int b) {
    #pragma unroll
    for (int q = 0; q < 4; ++q) {
      gl_lds16(wsA + aRowBase + (size_t)(q * 8 + rA) * 8192 + kt * 128 + pcA * 16,
               &As[b][(wid * 32 + q * 8) * 64]);
      gl_lds16(wsB + bRowBase + (size_t)(q * 8 + rA) * 8192 + kt * 128 + pcA * 16,
               &Bs[b][(wid * 32 + q * 8) * 64]);
    }
  };

  stage(0, 0);
  __syncthreads();                 // tile 0 resident (vmcnt(0) + barrier)

  for (int kt = 0; kt < 64; ++kt) {
    const int cur = kt & 1;

    // 1) fragments of tile kt -> regs. Outstanding vm-loads here are ZERO
    //    (previous barrier drained), so any compiler alias-wait is free.
    bf16x8 af2[2][4], bf2[2][4];
    #pragma unroll
    for (int s = 0; s < 2; ++s) {
      const int sw = ((s * 4 + quad) ^ (am & 7)) * 8;   // zero-conflict (verified)
      #pragma unroll
      for (int tm = 0; tm < 4; ++tm)
        af2[s][tm] = *(const bf16x8*)&As[cur][(wr * 64 + tm * 16 + am) * 64 + sw];
      #pragma unroll
      for (int tn = 0; tn < 4; ++tn)
        bf2[s][tn] = *(const bf16x8*)&Bs[cur][(wc * 64 + tn * 16 + am) * 64 + sw];
    }

    // 2) issue next tile into the OTHER buffer (no conflict with readers of
    //    cur; prev-iter readers of cur^1 finished at the last barrier).
    if (kt < 63) stage(kt + 1, cur ^ 1);
    __builtin_amdgcn_sched_barrier(0);   // keep stage-issue ahead of the MFMAs

    // 3) MFMAs from registers (compiler lgkmcnt-waits the ds_reads)
    #pragma unroll
    for (int s = 0; s < 2; ++s)
      #pragma unroll
      for (int tm = 0; tm < 4; ++tm)
        #pragma unroll
        for (int tn = 0; tn < 4; ++tn)
          acc[tm][tn] = __builtin_amdgcn_mfma_f32_16x16x32_bf16(
              af2[s][tm], bf2[s][tn], acc[tm][tn], 0, 0, 0);

    // 4) single barrier: per-wave vmcnt(0) drain of stage(kt+1) -- issued one
    //    full MFMA phase ago -- plus read-release of buffer cur.
    __syncthreads();
  }

  // ---- epilogue: coalesced cin stage, in-register gates, LDS-bounce stores ----
  const int BU = 1024 * 2048;
  const int ob = n * 1024 + u0;

  // cin -> CinL, fully coalesced (128B-aligned float4 runs). Independent LDS
  // region, so no ordering needed vs As/Bs until the barrier below.
  float4 cv[4];
  #pragma unroll
  for (int i = 0; i < 4; ++i) {
    const int idx = i * 256 + tid;
    const int row = idx >> 3, c4 = idx & 7;
    cv[i] = *(const float4*)&cin[(size_t)(rowbase + row) * 2048 + ob + c4 * 4];
  }
  #pragma unroll
  for (int i = 0; i < 4; ++i) ((float4*)CinL)[i * 256 + tid] = cv[i];
  __syncthreads();   // (a) all waves past K-loop; (b) CinL ready

  float* hL = (float*)&As[0][0];   // 128 rows x 32 u-cols (16 KB)
  float* cL = (float*)&Bs[0][0];

  const int g    = lane & 3;
  const int base = lane & ~3;
  #pragma unroll
  for (int tn = 0; tn < 4; ++tn) {
    const int cloc = (wc * 64 + tn * 16 + am) >> 2;   // 0..31, same for 4-lane group
    #pragma unroll
    for (int tm = 0; tm < 4; ++tm) {
      const int r0 = wr * 64 + tm * 16 + quad * 4;    // 0..127 local row
      #pragma unroll
      for (int r = 0; r < 4; ++r) {
        const float val = acc[tm][tn][r];
        const float xs  = (g == 2) ? 2.f * val : val;       // tanh via sigmoid
        const float sg  = 1.f / (1.f + __expf(-xs));
        const float act = (g == 2) ? (2.f * sg - 1.f) : sg;
        const float ig = __shfl(act, base + 0, 64);
        const float fg = __shfl(act, base + 1, 64);
        const float gg = __shfl(act, base + 2, 64);
        const float og = __shfl(act, base + 3, 64);
        const float cold = CinL[(r0 + r) * 32 + cloc];      // LDS broadcast
        const float nc = fg * cold + ig * gg;
        const float th = 1.f - 2.f / (1.f + __expf(2.f * nc));
        const float nh = og * th;
        if (g == 0) hL[(r0 + r) * 32 + cloc] = nh;
        if (g == 1) cL[(r0 + r) * 32 + cloc] = nc;
      }
    }
  }
  __syncthreads();

  // coalesced stores: per wave-instr 64 lanes x 16B = 8 rows x 128B aligned runs
  #pragma unroll
  for (int i = 0; i < 4; ++i) {
    const int idx = i * 256 + tid;
    const int row = idx >> 3, c4 = idx & 7;
    const size_t go = (size_t)(rowbase + row) * 2048 + ob + c4 * 4;
    *(float4*)&out[go]      = ((float4*)hL)[idx];
    *(float4*)&out[BU + go] = ((float4*)cL)[idx];
  }
}

// ---------- fallback: round-4 fused kernel (used when ws too small) ----------
__global__ __launch_bounds__(512, 4)
void lstm_fused_fb(const float* __restrict__ x, const float* __restrict__ h,
                   const float* __restrict__ cin, const float* __restrict__ W,
                   float* __restrict__ out)
{
  __shared__ short As[128 * 64];
  __shared__ short Bs[128 * 64];
  const int tid  = threadIdx.x;
  const int lane = tid & 63;
  const int wid  = tid >> 6;
  const int wr   = wid >> 2;
  const int wq   = wid & 3;
  const int bid     = blockIdx.x;
  const int rowblk  = bid >> 6;
  const int colblk  = bid & 63;
  const int n       = colblk >> 5;
  const int u0      = (colblk & 31) * 32;
  const int rowbase = rowblk * 128;
  const int ar = tid >> 2;
  const int aq = tid & 3;
  const int bc   = tid & 127;
  const int bgt  = bc & 3;
  const int bu   = bc >> 2;
  const int kgrp = tid >> 7;
  const int gcol = bgt * 1024 + u0 + bu;
  const int am   = lane & 15;
  const int quad = lane >> 4;

  f32x4 acc[4][2];
  const f32x4 zero = {0.f, 0.f, 0.f, 0.f};
  #pragma unroll
  for (int i = 0; i < 4; ++i)
    #pragma unroll
    for (int j = 0; j < 2; ++j) acc[i][j] = zero;

  float4 areg[4];
  float  breg[16];
  auto load_tiles = [&](int kt) {
    const int blk = kt >> 4;
    const float* asrc = (blk & 1) ? h : x;
    const int cb = (blk >> 1) * 1024 + (kt & 15) * 64;
    const float4* p = (const float4*)(asrc + (rowbase + ar) * 2048 + cb + aq * 16);
    #pragma unroll
    for (int q = 0; q < 4; ++q) areg[q] = p[q];
    const int kq = kt >> 5;
    const float* wp = W + ((kq * 2 + n) * 2048 + (kt & 31) * 64 + kgrp * 16) * 4096 + gcol;
    #pragma unroll
    for (int j = 0; j < 16; ++j) breg[j] = wp[j * 4096];
  };
  load_tiles(0);
  for (int kt = 0; kt < 64; ++kt) {
    bf16x8 aw[2];
    {
      pk8 p0, p1;
      p0.u[0] = pkcvt(areg[0].x, areg[0].y); p0.u[1] = pkcvt(areg[0].z, areg[0].w);
      p0.u[2] = pkcvt(areg[1].x, areg[1].y); p0.u[3] = pkcvt(areg[1].z, areg[1].w);
      p1.u[0] = pkcvt(areg[2].x, areg[2].y); p1.u[1] = pkcvt(areg[2].z, areg[2].w);
      p1.u[2] = pkcvt(areg[3].x, areg[3].y); p1.u[3] = pkcvt(areg[3].z, areg[3].w);
      aw[0] = p0.v; aw[1] = p1.v;
    }
    bf16x8 bw[2];
    {
      pk8 q0, q1;
      #pragma unroll
      for (int j = 0; j < 4; ++j) {
        q0.u[j] = pkcvt(breg[2 * j],     breg[2 * j + 1]);
        q1.u[j] = pkcvt(breg[8 + 2 * j], breg[8 + 2 * j + 1]);
      }
      bw[0] = q0.v; bw[1] = q1.v;
    }
    __syncthreads();
    #pragma unroll
    for (int hh = 0; hh < 2; ++hh)
      *(bf16x8*)&As[ar * 64 + (((aq * 2 + hh) ^ (ar & 7)) * 8)] = aw[hh];
    #pragma unroll
    for (int hh = 0; hh < 2; ++hh)
      *(bf16x8*)&Bs[bc * 64 + (((kgrp * 2 + hh) ^ (bc & 7)) * 8)] = bw[hh];
    __syncthreads();
    if (kt < 63) load_tiles(kt + 1);
    #pragma unroll
    for (int s = 0; s < 2; ++s) {
      const int sw = ((s * 4 + quad) ^ (am & 7)) * 8;
      bf16x8 af[4], bfr[2];
      #pragma unroll
      for (int tm = 0; tm < 4; ++tm)
        af[tm] = *(const bf16x8*)&As[(wr * 64 + tm * 16 + am) * 64 + sw];
      #pragma unroll
      for (int tn = 0; tn < 2; ++tn)
        bfr[tn] = *(const bf16x8*)&Bs[(wq * 32 + tn * 16 + am) * 64 + sw];
      #pragma unroll
      for (int tm = 0; tm < 4; ++tm)
        #pragma unroll
        for (int tn = 0; tn < 2; ++tn)
          acc[tm][tn] = __builtin_amdgcn_mfma_f32_16x16x32_bf16(
              af[tm], bfr[tn], acc[tm][tn], 0, 0, 0);
    }
  }
  const int BU   = 1024 * 2048;
  const int g    = lane & 3;
  const int base = lane & ~3;
  #pragma unroll
  for (int tn = 0; tn < 2; ++tn) {
    const int cil = wq * 32 + tn * 16 + am;
    const int col = n * 1024 + u0 + (cil >> 2);
    #pragma unroll
    for (int tm = 0; tm < 4; ++tm) {
      const int brow0 = rowbase + wr * 64 + tm * 16 + quad * 4;
      #pragma unroll
      for (int r = 0; r < 4; ++r) {
        const int brow = brow0 + r;
        const float val = acc[tm][tn][r];
        const float xs  = (g == 2) ? 2.f * val : val;
        const float sg  = 1.f / (1.f + __expf(-xs));
        const float act = (g == 2) ? (2.f * sg - 1.f) : sg;
        const float ig = __shfl(act, base + 0, 64);
        const float fg = __shfl(act, base + 1, 64);
        const float gg = __shfl(act, base + 2, 64);
        const float og = __shfl(act, base + 3, 64);
        const float cold = cin[brow * 2048 + col];
        const float nc = fg * cold + ig * gg;
        const float th = 1.f - 2.f / (1.f + __expf(2.f * nc));
        const float nh = og * th;
        if (g == 0) out[brow * 2048 + col]      = nh;
        if (g == 1) out[BU + brow * 2048 + col] = nc;
      }
    }
  }
}

extern "C" void kernel_launch(void* const* d_in, const int* in_sizes, int n_in,
                              void* d_out, int out_size, void* d_ws, size_t ws_size,
                              hipStream_t stream) {
  const float* x = (const float*)d_in[0];
  const float* h = (const float*)d_in[1];
  const float* c = (const float*)d_in[2];
  const float* W = (const float*)d_in[3];
  float* out = (float*)d_out;

  const size_t WSA_BYTES = (size_t)1024 * 4096 * 2;        //  8 MB bf16 xh
  const size_t WSB_BYTES = (size_t)2 * 4096 * 4096 * 2;    // 67 MB bf16 W^T
  if (ws_size >= WSA_BYTES + WSB_BYTES) {
    char* wsA = (char*)d_ws;
    char* wsB = (char*)d_ws + WSA_BYTES;
    // blocks 0..2047: W transpose (long pole, dispatched first);
    // blocks 2048..4095: xh convert (backfills, overlaps the W stream).
    prep_all<<<dim3(4096), dim3(256), 0, stream>>>(x, h, W, wsA, wsB);
    lstm_mm<<<dim3(512), dim3(256), 0, stream>>>(wsA, wsB, c, out);
  } else {
    lstm_fused_fb<<<dim3(512), dim3(512), 0, stream>>>(x, h, c, W, out);
  }
}